// Round 1
// baseline (346.513 us; speedup 1.0000x reference)
//
#include <hip/hip_runtime.h>
#include <hip/hip_bf16.h>

typedef __attribute__((ext_vector_type(8))) short bf16x8;
typedef __attribute__((ext_vector_type(4))) float f32x4;

#define MFMA16(a, b, c) __builtin_amdgcn_mfma_f32_16x16x32_bf16(a, b, c, 0, 0, 0)

static constexpr int Bn = 2;
static constexpr int S  = 4096;   // H*W
static constexpr int C  = 512;
static constexpr int NH = 8;
static constexpr int HD = 64;
static constexpr int M  = Bn * S; // 8192

__device__ __forceinline__ ushort f2bf(float f) {
  unsigned u = __builtin_bit_cast(unsigned, f);
  u += 0x7fffu + ((u >> 16) & 1u);
  return (ushort)(u >> 16);
}

// ---------------- GroupNorm stats: one block per (b, group) ----------------
__global__ __launch_bounds__(256) void gn_stats_kernel(const float* __restrict__ x,
                                                       float2* __restrict__ stats) {
  int bg = blockIdx.x;            // 0..63
  int b = bg >> 5, g = bg & 31;
  const float* xp = x + (size_t)b * S * C + g * 16;
  float sum = 0.f, sq = 0.f;
  for (int s = threadIdx.x; s < S; s += 256) {
    const float4* p = (const float4*)(xp + (size_t)s * C);
    #pragma unroll
    for (int i = 0; i < 4; i++) {
      float4 v = p[i];
      sum += v.x + v.y + v.z + v.w;
      sq  += v.x * v.x + v.y * v.y + v.z * v.z + v.w * v.w;
    }
  }
  #pragma unroll
  for (int d = 1; d < 64; d <<= 1) {
    sum += __shfl_xor(sum, d);
    sq  += __shfl_xor(sq, d);
  }
  __shared__ float2 red[4];
  if ((threadIdx.x & 63) == 0) red[threadIdx.x >> 6] = make_float2(sum, sq);
  __syncthreads();
  if (threadIdx.x == 0) {
    float s0 = 0.f, q0 = 0.f;
    #pragma unroll
    for (int i = 0; i < 4; i++) { s0 += red[i].x; q0 += red[i].y; }
    float inv = 1.f / (float)(S * 16);
    float mean = s0 * inv;
    float var = q0 * inv - mean * mean;
    stats[bg] = make_float2(mean, rsqrtf(var + 1e-6f));
  }
}

// ---------------- GroupNorm apply + cast to bf16 ----------------
__global__ __launch_bounds__(256) void gn_apply_kernel(const float* __restrict__ x,
                                                       const float* __restrict__ sc,
                                                       const float* __restrict__ bi,
                                                       const float2* __restrict__ stats,
                                                       ushort* __restrict__ h) {
  int i = blockIdx.x * 256 + threadIdx.x;   // 0..524287, 8 channels each
  int s = i >> 6;
  int c0 = (i & 63) << 3;
  int b = s >> 12;
  float2 st = stats[(b << 5) + (c0 >> 4)];
  const float4* xv = (const float4*)(x + (size_t)s * C + c0);
  const float4* sv = (const float4*)(sc + c0);
  const float4* bv = (const float4*)(bi + c0);
  float4 a0 = xv[0], a1 = xv[1];
  float4 s0 = sv[0], s1 = sv[1];
  float4 b0 = bv[0], b1 = bv[1];
  uint4 pk;
  pk.x = (unsigned)f2bf((a0.x - st.x) * st.y * s0.x + b0.x) |
         ((unsigned)f2bf((a0.y - st.x) * st.y * s0.y + b0.y) << 16);
  pk.y = (unsigned)f2bf((a0.z - st.x) * st.y * s0.z + b0.z) |
         ((unsigned)f2bf((a0.w - st.x) * st.y * s0.w + b0.w) << 16);
  pk.z = (unsigned)f2bf((a1.x - st.x) * st.y * s1.x + b1.x) |
         ((unsigned)f2bf((a1.y - st.x) * st.y * s1.y + b1.y) << 16);
  pk.w = (unsigned)f2bf((a1.z - st.x) * st.y * s1.z + b1.z) |
         ((unsigned)f2bf((a1.w - st.x) * st.y * s1.w + b1.w) << 16);
  *(uint4*)(h + (size_t)i * 8) = pk;
}

// ---------------- weight transpose + cast: [512][512] f32 -> [512][512]^T bf16 ----------------
__global__ __launch_bounds__(256) void wtrans_kernel(const float* __restrict__ w0,
                                                     const float* __restrict__ w1,
                                                     const float* __restrict__ w2,
                                                     const float* __restrict__ w3,
                                                     ushort* __restrict__ wT) {
  __shared__ float tile[64][65];
  int mat = blockIdx.y;
  const float* w = (mat == 0) ? w0 : (mat == 1) ? w1 : (mat == 2) ? w2 : w3;
  int tr = (blockIdx.x >> 3) * 64;  // source row block
  int tc = (blockIdx.x & 7) * 64;   // source col block
  int ty = threadIdx.x >> 6, tx = threadIdx.x & 63;
  #pragma unroll
  for (int i = 0; i < 16; i++) {
    int r = i * 4 + ty;
    tile[r][tx] = w[(size_t)(tr + r) * 512 + tc + tx];
  }
  __syncthreads();
  #pragma unroll
  for (int i = 0; i < 16; i++) {
    int r = i * 4 + ty;  // output row = tc + r
    wT[((size_t)mat << 18) + (size_t)(tc + r) * 512 + tr + tx] = f2bf(tile[tx][r]);
  }
}

// ---------------- fused QKV GEMM: [8192x512] x [512x1536] ----------------
__global__ __launch_bounds__(256) void qkv_gemm_kernel(const ushort* __restrict__ h,
                                                       const ushort* __restrict__ wT,
                                                       const float* __restrict__ bq,
                                                       const float* __restrict__ bk,
                                                       const float* __restrict__ bv,
                                                       ushort* __restrict__ qo,
                                                       ushort* __restrict__ ko,
                                                       ushort* __restrict__ vT) {
  const int l = threadIdx.x & 63;
  const int w = threadIdx.x >> 6;
  const int lr = l & 15, lg = l >> 4;
  const int m0 = blockIdx.x * 128 + (w >> 1) * 64;
  const int n0 = blockIdx.y * 128 + (w & 1) * 64;

  const ushort* ap = h  + (size_t)(m0 + lr) * C + lg * 8;
  const ushort* bp = wT + (size_t)(n0 + lr) * C + lg * 8;

  f32x4 acc[4][4] = {};
  for (int k = 0; k < C; k += 32) {
    bf16x8 af[4], bfr[4];
    #pragma unroll
    for (int i = 0; i < 4; i++) af[i]  = *(const bf16x8*)(ap + (size_t)i * 16 * C + k);
    #pragma unroll
    for (int i = 0; i < 4; i++) bfr[i] = *(const bf16x8*)(bp + (size_t)i * 16 * C + k);
    #pragma unroll
    for (int mi = 0; mi < 4; mi++)
      #pragma unroll
      for (int ni = 0; ni < 4; ni++)
        acc[mi][ni] = MFMA16(af[mi], bfr[ni], acc[mi][ni]);
  }

  const int mat = n0 >> 9;  // uniform per block
  #pragma unroll
  for (int mi = 0; mi < 4; mi++) {
    #pragma unroll
    for (int ni = 0; ni < 4; ni++) {
      #pragma unroll
      for (int r = 0; r < 4; r++) {
        int srow = m0 + mi * 16 + lg * 4 + r;
        int nl = (n0 + ni * 16 + lr) & 511;
        float v = acc[mi][ni][r];
        if (mat == 0) {
          qo[(size_t)srow * C + nl] = f2bf((v + bq[nl]) * 0.125f);
        } else if (mat == 1) {
          ko[(size_t)srow * C + nl] = f2bf(v + bk[nl]);
        } else {
          vT[((size_t)(srow >> 12) * C + nl) * S + (srow & (S - 1))] = f2bf(v + bv[nl]);
        }
      }
    }
  }
}

// ---------------- flash attention: 4 waves/block, 32 q-rows/wave, 64-key tiles ----------------
__global__ __launch_bounds__(256) void attn_kernel(const ushort* __restrict__ q,
                                                   const ushort* __restrict__ k,
                                                   const ushort* __restrict__ vT,
                                                   ushort* __restrict__ o) {
  __shared__ ushort Plds[4][32][64];
  const int l = threadIdx.x & 63;
  const int wid = threadIdx.x >> 6;
  const int lr = l & 15, lg = l >> 4;
  const int bh = blockIdx.y;           // 0..15
  const int b = bh >> 3, hh = bh & 7;
  const int q0 = blockIdx.x * 128 + wid * 32;

  const ushort* qp = q + ((size_t)(b * S + q0)) * C + hh * HD;
  const ushort* kp = k + ((size_t)(b * S)) * C + hh * HD;
  const ushort* vp = vT + ((size_t)(b * C) + hh * HD) * S;

  bf16x8 qa[2][2];
  #pragma unroll
  for (int mi = 0; mi < 2; mi++)
    #pragma unroll
    for (int kk = 0; kk < 2; kk++)
      qa[mi][kk] = *(const bf16x8*)(qp + (size_t)(mi * 16 + lr) * C + kk * 32 + lg * 8);

  f32x4 oacc[2][4] = {};
  float mstate[2][4], lstate[2][4];
  #pragma unroll
  for (int mi = 0; mi < 2; mi++)
    #pragma unroll
    for (int r = 0; r < 4; r++) { mstate[mi][r] = -1e30f; lstate[mi][r] = 0.f; }

  for (int kt = 0; kt < S / 64; kt++) {
    // S-tile = Q * K^T   (32 q-rows x 64 keys)
    f32x4 sacc[2][4] = {};
    #pragma unroll
    for (int ni = 0; ni < 4; ni++) {
      #pragma unroll
      for (int kk = 0; kk < 2; kk++) {
        bf16x8 kf = *(const bf16x8*)(kp + (size_t)(kt * 64 + ni * 16 + lr) * C + kk * 32 + lg * 8);
        #pragma unroll
        for (int mi = 0; mi < 2; mi++)
          sacc[mi][ni] = MFMA16(qa[mi][kk], kf, sacc[mi][ni]);
      }
    }
    // online softmax
    #pragma unroll
    for (int mi = 0; mi < 2; mi++) {
      #pragma unroll
      for (int r = 0; r < 4; r++) {
        float mx = fmaxf(fmaxf(sacc[mi][0][r], sacc[mi][1][r]),
                         fmaxf(sacc[mi][2][r], sacc[mi][3][r]));
        #pragma unroll
        for (int d = 1; d < 16; d <<= 1) mx = fmaxf(mx, __shfl_xor(mx, d));
        float mnew = fmaxf(mstate[mi][r], mx);
        float a = __expf(mstate[mi][r] - mnew);
        float ps = 0.f;
        #pragma unroll
        for (int ni = 0; ni < 4; ni++) {
          float p = __expf(sacc[mi][ni][r] - mnew);
          sacc[mi][ni][r] = p;
          ps += p;
        }
        #pragma unroll
        for (int d = 1; d < 16; d <<= 1) ps += __shfl_xor(ps, d);
        lstate[mi][r] = lstate[mi][r] * a + ps;
        mstate[mi][r] = mnew;
        #pragma unroll
        for (int nd = 0; nd < 4; nd++) oacc[mi][nd][r] *= a;
      }
    }
    // P -> LDS (bf16, XOR-swizzled rows)
    #pragma unroll
    for (int mi = 0; mi < 2; mi++)
      #pragma unroll
      for (int ni = 0; ni < 4; ni++)
        #pragma unroll
        for (int r = 0; r < 4; r++) {
          int row = mi * 16 + lg * 4 + r;
          int col = ni * 16 + lr;
          Plds[wid][row][col ^ ((row & 7) << 3)] = f2bf(sacc[mi][ni][r]);
        }
    // O += P * V
    #pragma unroll
    for (int kk = 0; kk < 2; kk++) {
      bf16x8 pa[2];
      #pragma unroll
      for (int mi = 0; mi < 2; mi++) {
        int row = mi * 16 + lr;
        pa[mi] = *(const bf16x8*)&Plds[wid][row][(kk * 32 + lg * 8) ^ ((row & 7) << 3)];
      }
      #pragma unroll
      for (int nd = 0; nd < 4; nd++) {
        bf16x8 vf = *(const bf16x8*)(vp + (size_t)(nd * 16 + lr) * S + kt * 64 + kk * 32 + lg * 8);
        #pragma unroll
        for (int mi = 0; mi < 2; mi++)
          oacc[mi][nd] = MFMA16(pa[mi], vf, oacc[mi][nd]);
      }
    }
  }
  // epilogue: divide by l, store bf16
  ushort* op = o + ((size_t)(b * S + q0)) * C + hh * HD;
  #pragma unroll
  for (int mi = 0; mi < 2; mi++)
    #pragma unroll
    for (int nd = 0; nd < 4; nd++)
      #pragma unroll
      for (int r = 0; r < 4; r++) {
        float val = oacc[mi][nd][r] / lstate[mi][r];
        op[(size_t)(mi * 16 + lg * 4 + r) * C + nd * 16 + lr] = f2bf(val);
      }
}

// ---------------- O-projection + bias + residual ----------------
__global__ __launch_bounds__(256) void oproj_gemm_kernel(const ushort* __restrict__ o,
                                                         const ushort* __restrict__ woT,
                                                         const float* __restrict__ x,
                                                         const float* __restrict__ bo,
                                                         float* __restrict__ out) {
  const int l = threadIdx.x & 63;
  const int w = threadIdx.x >> 6;
  const int lr = l & 15, lg = l >> 4;
  const int m0 = blockIdx.x * 128 + (w >> 1) * 64;
  const int n0 = blockIdx.y * 128 + (w & 1) * 64;

  const ushort* ap = o   + (size_t)(m0 + lr) * C + lg * 8;
  const ushort* bp = woT + (size_t)(n0 + lr) * C + lg * 8;

  f32x4 acc[4][4] = {};
  for (int k = 0; k < C; k += 32) {
    bf16x8 af[4], bfr[4];
    #pragma unroll
    for (int i = 0; i < 4; i++) af[i]  = *(const bf16x8*)(ap + (size_t)i * 16 * C + k);
    #pragma unroll
    for (int i = 0; i < 4; i++) bfr[i] = *(const bf16x8*)(bp + (size_t)i * 16 * C + k);
    #pragma unroll
    for (int mi = 0; mi < 4; mi++)
      #pragma unroll
      for (int ni = 0; ni < 4; ni++)
        acc[mi][ni] = MFMA16(af[mi], bfr[ni], acc[mi][ni]);
  }

  #pragma unroll
  for (int mi = 0; mi < 4; mi++) {
    #pragma unroll
    for (int ni = 0; ni < 4; ni++) {
      #pragma unroll
      for (int r = 0; r < 4; r++) {
        int srow = m0 + mi * 16 + lg * 4 + r;
        int c = n0 + ni * 16 + lr;
        out[(size_t)srow * C + c] = x[(size_t)srow * C + c] + acc[mi][ni][r] + bo[c];
      }
    }
  }
}

extern "C" void kernel_launch(void* const* d_in, const int* in_sizes, int n_in,
                              void* d_out, int out_size, void* d_ws, size_t ws_size,
                              hipStream_t stream) {
  const float* x  = (const float*)d_in[0];
  const float* gs = (const float*)d_in[1];
  const float* gb = (const float*)d_in[2];
  const float* wq = (const float*)d_in[3];
  const float* bq = (const float*)d_in[4];
  const float* wk = (const float*)d_in[5];
  const float* bk = (const float*)d_in[6];
  const float* wv = (const float*)d_in[7];
  const float* bv = (const float*)d_in[8];
  const float* wo = (const float*)d_in[9];
  const float* bo = (const float*)d_in[10];

  char* ws = (char*)d_ws;
  ushort* h    = (ushort*)(ws);                    // 8 MB  [M][C] bf16
  ushort* wT   = (ushort*)(ws + 8388608);          // 2 MB  [1536+512][512] bf16 (wqT,wkT,wvT,woT)
  ushort* qb   = (ushort*)(ws + 10485760);         // 8 MB  [M][512] bf16 (pre-scaled by 1/8)
  ushort* kb   = (ushort*)(ws + 18874368);         // 8 MB  [M][512] bf16
  ushort* vTb  = (ushort*)(ws + 27262976);         // 8 MB  [B][512][S] bf16 (transposed)
  ushort* ob   = (ushort*)(ws + 35651584);         // 8 MB  [M][512] bf16
  float2* st   = (float2*)(ws + 44040192);         // 512 B

  gn_stats_kernel<<<64, 256, 0, stream>>>(x, st);
  wtrans_kernel<<<dim3(64, 4), 256, 0, stream>>>(wq, wk, wv, wo, wT);
  gn_apply_kernel<<<2048, 256, 0, stream>>>(x, gs, gb, st, h);
  qkv_gemm_kernel<<<dim3(64, 12), 256, 0, stream>>>(h, wT, bq, bk, bv, qb, kb, vTb);
  attn_kernel<<<dim3(32, 16), 256, 0, stream>>>(qb, kb, vTb, ob);
  oproj_gemm_kernel<<<dim3(64, 4), 256, 0, stream>>>(ob, wT + 786432, x, bo, (float*)d_out);
}